// Round 7
// baseline (461.665 us; speedup 1.0000x reference)
//
#include <hip/hip_runtime.h>
#include <math.h>

// Problem constants (reference file)
#define NPTS   500000
#define CIN    16
#define COUT   64
#define PE     32
#define GRID_H 256
#define GRID_W 256
#define NCELL  (GRID_H * GRID_W)   // 65536

// ws layout (bytes)
#define WS_HIST   0                      // 65536 u32  (256 KB)
#define WS_OFFS   262144                 // 65536 u32  (256 KB)
#define WS_SORT   524288                 // 500000 i32 (2 MB)
#define WS_WPK    2524288                // 18432 f16 frag-packed weights (36864 B)
#define WS_PART   2561152                // 256 u32 block partials (1 KB)

#define PT_BLOCKS ((NPTS + 255) / 256)   // 1954 (aux kernels, 256 thr)
#define MB_BLOCKS ((NPTS + 511) / 512)   // 977  (main kernel, 512 thr)

#define W_HALFS   18432                  // (7+2)*4 frags * 64 lanes * 8 halfs
#define W1_FRAGS  28                     // 7 k-steps * 4 ch-tiles
#define H_STRIDE  72                     // halfs per staged row (144 B, 16B-aligned)
#define PS_WAVE   (16 * H_STRIDE)        // per-wave P staging (16 rows)

typedef _Float16 f16x8 __attribute__((ext_vector_type(8)));
typedef float    f32x4 __attribute__((ext_vector_type(4)));

__device__ __forceinline__ int cell_index(float v) {
    float nf = fminf(fmaxf((v + 1.0f) * 0.5f, 0.0f), 1.0f);
    int i = (int)floorf(nf * 256.0f);
    return i > 255 ? 255 : i;
}

__device__ __forceinline__ int flat_of(const float* pos, int p, int a1, int a2) {
    float pa1 = pos[p * 3 + a1];
    float pa2 = pos[p * 3 + a2];
    return cell_index(pa1) * GRID_W + cell_index(pa2);
}

// K0: fused weight-pack (B-fragment order) + cell histogram.
// B-frag (16x16x32): lane holds B[k][n], n = lane&15, k = (lane>>4)*8 + j.
__global__ void pack_hist_kernel(const float* __restrict__ W1,
                                 const float* __restrict__ W2,
                                 const float* __restrict__ pos,
                                 const int* __restrict__ ax1p,
                                 const int* __restrict__ ax2p,
                                 _Float16* __restrict__ wpk,
                                 unsigned int* __restrict__ hist)
{
    int i = blockIdx.x * 256 + threadIdx.x;
    if (i < W_HALFS) {
        int j = i & 7, lane = (i >> 3) & 63, f = i >> 9;
        int k  = ((f < W1_FRAGS) ? (f >> 2) : ((f - W1_FRAGS) >> 2)) * 32 + ((lane >> 4) << 3) + j;
        int ch = (f & 3) * 16 + (lane & 15);
        float v;
        if (f < W1_FRAGS) v = (k < 208) ? W1[k * 64 + ch] : 0.0f;
        else              v = W2[k * 64 + ch];
        wpk[i] = (_Float16)v;
    }
    if (i < NPTS)
        atomicAdd(&hist[flat_of(pos, i, ax1p[0], ax2p[0])], 1u);
}

// K1a: per-256-cell-chunk sums (coalesced)
__global__ void scan_sum_kernel(const unsigned int* __restrict__ hist,
                                unsigned int* __restrict__ part)
{
    __shared__ unsigned int sc[256];
    const int t = threadIdx.x;
    sc[t] = hist[blockIdx.x * 256 + t];
    __syncthreads();
    for (int off = 128; off > 0; off >>= 1) {
        if (t < off) sc[t] += sc[t + off];
        __syncthreads();
    }
    if (t == 0) part[blockIdx.x] = sc[0];
}

// K1b: exclusive scan of the 256 partials (single tiny block)
__global__ void scan_top_kernel(unsigned int* __restrict__ part)
{
    __shared__ unsigned int sc[256];
    const int t = threadIdx.x;
    unsigned int v = part[t];
    sc[t] = v;
    __syncthreads();
    for (int off = 1; off < 256; off <<= 1) {
        unsigned int add = (t >= off) ? sc[t - off] : 0u;
        __syncthreads();
        sc[t] += add;
        __syncthreads();
    }
    part[t] = sc[t] - v;   // exclusive
}

// K1c: per-chunk exclusive scan + chunk base -> offs (coalesced)
__global__ void scan_apply_kernel(const unsigned int* __restrict__ hist,
                                  const unsigned int* __restrict__ part,
                                  unsigned int* __restrict__ offs)
{
    __shared__ unsigned int sc[256];
    const int t = threadIdx.x;
    unsigned int v = hist[blockIdx.x * 256 + t];
    sc[t] = v;
    __syncthreads();
    for (int off = 1; off < 256; off <<= 1) {
        unsigned int add = (t >= off) ? sc[t - off] : 0u;
        __syncthreads();
        sc[t] += add;
        __syncthreads();
    }
    offs[blockIdx.x * 256 + t] = sc[t] - v + part[blockIdx.x];
}

// K2: scatter point ids into sorted order (offs mutated into running cursors)
__global__ void scatter_kernel(const float* __restrict__ pos,
                               const int* __restrict__ ax1p,
                               const int* __restrict__ ax2p,
                               unsigned int* __restrict__ offs,
                               int* __restrict__ sorted)
{
    int p = blockIdx.x * 256 + threadIdx.x;
    if (p >= NPTS) return;
    int flat = flat_of(pos, p, ax1p[0], ax2p[0]);
    unsigned int dst = atomicAdd(&offs[flat], 1u);
    sorted[dst] = p;
}

// K3: MFMA MLP + in-register segmented reduction.
// Wave = 64 points (4 row-tiles of 16). A-frags in registers, B-frags
// lane-linear from frag-order LDS. LN via 16-lane xor-shuffle. Epilogue
// reduces D2 from registers via quad shuffles -> 1 atomic/(run,channel).
__global__ __launch_bounds__(512, 4)
void mlp_mfma_kernel(const float* __restrict__ pos,
                     const float* __restrict__ feats,
                     const _Float16* __restrict__ wpk,
                     const float* __restrict__ b1,
                     const float* __restrict__ ln_g,
                     const float* __restrict__ ln_b,
                     const float* __restrict__ b2,
                     const int*   __restrict__ ax1p,
                     const int*   __restrict__ ax2p,
                     const int*   __restrict__ sorted,
                     float* __restrict__ outSums)   // [COUT][NCELL] == d_out
{
    __shared__ __align__(16) _Float16 WF[W_HALFS];        // 36864 B
    __shared__ __align__(16) _Float16 PS[8 * PS_WAVE];    // 18432 B (per-wave 16 rows)

    // stage frag-packed weights (coalesced 16B copies)
    {
        const uint4* src = (const uint4*)wpk;
        uint4* dst = (uint4*)WF;
        for (int i = threadIdx.x; i < W_HALFS / 8; i += 512) dst[i] = src[i];
    }

    const int lane = threadIdx.x & 63;
    const int wv   = threadIdx.x >> 6;
    const int g    = lane >> 4;        // quad
    const int n    = lane & 15;
    _Float16* Pw = PS + wv * PS_WAVE;

    const int slot   = blockIdx.x * 512 + threadIdx.x;
    const bool valid = (slot < NPTS);
    const int a1 = ax1p[0], a2 = ax2p[0];
    int myc;
    {
        int p0 = valid ? sorted[slot] : 0;
        myc = valid ? flat_of(pos, p0, a1, a2) : 0x7FFFFFFF;
    }
    // run-head bitmask for this wave (uniform)
    int prevc = __shfl_up(myc, 1);
    unsigned long long heads = __ballot(lane == 0 || myc != prevc);

    // per-channel params for ch = n + 16c
    float b1v[4], b2v[4], lgv[4], lbv[4];
    #pragma unroll
    for (int c = 0; c < 4; ++c) {
        int ch = n + 16 * c;
        b1v[c] = b1[ch]; b2v[c] = b2[ch]; lgv[c] = ln_g[ch]; lbv[c] = ln_b[ch];
    }

    // per-tile point data: lane serves point (t*16 + n)
    int   pt[4];
    float ppx[4], ppy[4], ppz[4];
    const int wbase = blockIdx.x * 512 + wv * 64;
    #pragma unroll
    for (int t = 0; t < 4; ++t) {
        int st = wbase + t * 16 + n;
        int p  = (st < NPTS) ? sorted[st] : 0;
        pt[t]  = p;
        ppx[t] = pos[3 * p + 0];
        ppy[t] = pos[3 * p + 1];
        ppz[t] = pos[3 * p + 2];
    }

    // prefetch feats (used by g<2 lanes in s=0) — issue all 8 loads up front
    float4 fA[4], fB[4];
    if (g < 2) {
        #pragma unroll
        for (int t = 0; t < 4; ++t) {
            const float4* fr = (const float4*)(feats + (size_t)pt[t] * CIN + g * 8);
            fA[t] = fr[0]; fB[t] = fr[1];
        }
    }

    __syncthreads();   // WF visible

    // ---- GEMM1: acc[t][c] (16 pts x 16 ch), K = 224 (208 + zero pad) ------
    f32x4 acc[4][4];
    #pragma unroll
    for (int t = 0; t < 4; ++t)
        #pragma unroll
        for (int c = 0; c < 4; ++c)
            acc[t][c] = (f32x4){0.0f, 0.0f, 0.0f, 0.0f};

    #pragma unroll
    for (int s = 0; s < 7; ++s) {
        f16x8 af[4];
        #pragma unroll
        for (int t = 0; t < 4; ++t) {
            int k0 = s * 32 + g * 8;
            f16x8 a;
            if (s == 0 && g < 2) {               // feats rows (prefetched)
                a[0] = (_Float16)fA[t].x; a[1] = (_Float16)fA[t].y;
                a[2] = (_Float16)fA[t].z; a[3] = (_Float16)fA[t].w;
                a[4] = (_Float16)fB[t].x; a[5] = (_Float16)fB[t].y;
                a[6] = (_Float16)fB[t].z; a[7] = (_Float16)fB[t].w;
            } else if (k0 >= 208) {              // zero pad (s==6, g>=2)
                #pragma unroll
                for (int j = 0; j < 8; ++j) a[j] = (_Float16)0.0f;
            } else {                             // PE: e = k0-16 = d*64+sc*32+f0
                int e  = k0 - 16;
                int d  = e >> 6;
                int sc = (e >> 5) & 1;
                int f0 = e & 31;
                float pv  = (d == 0) ? ppx[t] : ((d == 1) ? ppy[t] : ppz[t]);
                float ang = pv * 1.57079632679489662f * exp2f((float)f0 * 0.03125f);
                #pragma unroll
                for (int j = 0; j < 8; ++j) {
                    float v = sc ? __cosf(ang) : __sinf(ang);
                    a[j] = (_Float16)v;
                    ang *= 1.02189714865411668f;   // 2^(1/32)
                }
            }
            af[t] = a;
        }
        #pragma unroll
        for (int c = 0; c < 4; ++c) {
            f16x8 bf = ((const f16x8*)WF)[(s * 4 + c) * 64 + lane];
            #pragma unroll
            for (int t = 0; t < 4; ++t)
                acc[t][c] = __builtin_amdgcn_mfma_f32_16x16x32_f16(af[t], bf, acc[t][c], 0, 0, 0);
        }
    }

    // ---- per tile: LN + GELU -> PS, GEMM2, in-register segmented reduce ---
    // D layout: lane holds D[row = 4g + r][ch = n + 16c], r = 0..3
    #pragma unroll
    for (int t = 0; t < 4; ++t) {
        // bias + LN stats
        f32x4 s1 = (f32x4){0.0f, 0.0f, 0.0f, 0.0f};
        f32x4 s2 = (f32x4){0.0f, 0.0f, 0.0f, 0.0f};
        #pragma unroll
        for (int c = 0; c < 4; ++c) {
            #pragma unroll
            for (int r = 0; r < 4; ++r) {
                float x = acc[t][c][r] + b1v[c];
                acc[t][c][r] = x;
                s1[r] += x;
                s2[r] += x * x;
            }
        }
        #pragma unroll
        for (int m = 1; m <= 8; m <<= 1) {
            #pragma unroll
            for (int r = 0; r < 4; ++r) {
                s1[r] += __shfl_xor(s1[r], m);
                s2[r] += __shfl_xor(s2[r], m);
            }
        }
        // GELU -> per-wave P staging (16 rows)
        #pragma unroll
        for (int r = 0; r < 4; ++r) {
            float mu   = s1[r] * (1.0f / 64.0f);
            float var  = s2[r] * (1.0f / 64.0f) - mu * mu;
            float rstd = __builtin_amdgcn_rsqf(var + 1e-5f);
            int lrow = 4 * g + r;
            #pragma unroll
            for (int c = 0; c < 4; ++c) {
                float x  = (acc[t][c][r] - mu) * rstd * lgv[c] + lbv[c];
                float u  = x * (0.7978845608028654f + 0.0356774081363001f * x * x);
                float e  = __expf(2.0f * u);
                float th = 1.0f - 2.0f * __builtin_amdgcn_rcpf(e + 1.0f);
                float gv = 0.5f * x * (1.0f + th);
                Pw[lrow * H_STRIDE + n + 16 * c] = (_Float16)gv;
            }
        }

        // GEMM2 for this tile
        f32x4 acc2[4];
        #pragma unroll
        for (int c = 0; c < 4; ++c) acc2[c] = (f32x4){0.0f, 0.0f, 0.0f, 0.0f};
        #pragma unroll
        for (int s = 0; s < 2; ++s) {
            f16x8 a2f = *(const f16x8*)(Pw + n * H_STRIDE + s * 32 + g * 8);
            #pragma unroll
            for (int c = 0; c < 4; ++c) {
                f16x8 bf = ((const f16x8*)WF)[(W1_FRAGS + s * 4 + c) * 64 + lane];
                acc2[c] = __builtin_amdgcn_mfma_f32_16x16x32_f16(a2f, bf, acc2[c], 0, 0, 0);
            }
        }
        #pragma unroll
        for (int c = 0; c < 4; ++c)
            #pragma unroll
            for (int r = 0; r < 4; ++r)
                acc2[c][r] += b2v[c];

        // segmented reduction over this tile's 16 rows (runs split at tiles)
        unsigned int ht = (unsigned int)((heads >> (t * 16)) & 0xFFFFull) | 1u;
        int s = 0;
        while (s < 16) {
            unsigned int rem = ht & ~((2u << s) - 1u);   // head bits above s
            int e = rem ? (__ffs(rem) - 1) : 16;
            int cellr = __shfl(myc, t * 16 + s);         // uniform src lane
            f32x4 part;
            #pragma unroll
            for (int c = 0; c < 4; ++c) {
                float pc = 0.0f;
                #pragma unroll
                for (int r = 0; r < 4; ++r) {
                    int row = 4 * g + r;
                    pc += (row >= s && row < e) ? acc2[c][r] : 0.0f;
                }
                pc += __shfl_xor(pc, 16);
                pc += __shfl_xor(pc, 32);
                part[c] = pc;
            }
            if (g == 0 && cellr != 0x7FFFFFFF) {
                #pragma unroll
                for (int c = 0; c < 4; ++c)
                    unsafeAtomicAdd(&outSums[(n + 16 * c) * NCELL + cellr], part[c]);
            }
            s = e;
        }
    }
}

// K4: divide by counts, in place on d_out
__global__ void finalize_kernel(float* __restrict__ out,
                                const unsigned int* __restrict__ hist)
{
    int t = blockIdx.x * 256 + threadIdx.x;   // grid sized exactly 64*NCELL/256
    float c = (float)hist[t & (NCELL - 1)];
    out[t] = out[t] / fmaxf(c, 1.0f);
}

extern "C" void kernel_launch(void* const* d_in, const int* in_sizes, int n_in,
                              void* d_out, int out_size, void* d_ws, size_t ws_size,
                              hipStream_t stream) {
    (void)in_sizes; (void)n_in; (void)out_size; (void)ws_size;
    const float* pos   = (const float*)d_in[0];
    const float* feats = (const float*)d_in[1];
    const float* W1    = (const float*)d_in[2];
    const float* b1    = (const float*)d_in[3];
    const float* ln_g  = (const float*)d_in[4];
    const float* ln_b  = (const float*)d_in[5];
    const float* W2    = (const float*)d_in[6];
    const float* b2    = (const float*)d_in[7];
    const int*   ax1   = (const int*)d_in[8];
    const int*   ax2   = (const int*)d_in[9];

    char* ws = (char*)d_ws;
    unsigned int* hist   = (unsigned int*)(ws + WS_HIST);
    unsigned int* offs   = (unsigned int*)(ws + WS_OFFS);
    int*          sorted = (int*)(ws + WS_SORT);
    _Float16*     wpk    = (_Float16*)(ws + WS_WPK);
    unsigned int* part   = (unsigned int*)(ws + WS_PART);

    float* out = (float*)d_out;   // accumulates sums in [COUT][NCELL]

    hipMemsetAsync(d_out, 0, (size_t)COUT * NCELL * sizeof(float), stream);
    hipMemsetAsync(hist, 0, NCELL * sizeof(unsigned int), stream);

    pack_hist_kernel<<<PT_BLOCKS, 256, 0, stream>>>(W1, W2, pos, ax1, ax2, wpk, hist);
    scan_sum_kernel<<<256, 256, 0, stream>>>(hist, part);
    scan_top_kernel<<<1, 256, 0, stream>>>(part);
    scan_apply_kernel<<<256, 256, 0, stream>>>(hist, part, offs);
    scatter_kernel<<<PT_BLOCKS, 256, 0, stream>>>(pos, ax1, ax2, offs, sorted);
    mlp_mfma_kernel<<<MB_BLOCKS, 512, 0, stream>>>(
        pos, feats, wpk, b1, ln_g, ln_b, b2, ax1, ax2, sorted, out);
    finalize_kernel<<<(COUT * NCELL) / 256, 256, 0, stream>>>(out, hist);
}

// Round 8
// 251.876 us; speedup vs baseline: 1.8329x; 1.8329x over previous
//
#include <hip/hip_runtime.h>
#include <math.h>

// Problem constants (reference file)
#define NPTS   500000
#define CIN    16
#define COUT   64
#define PE     32
#define GRID_H 256
#define GRID_W 256
#define NCELL  (GRID_H * GRID_W)   // 65536

// ws layout (bytes)
#define WS_HIST   0                      // 65536 u32  (256 KB)
#define WS_CUR    262144                 // 65536 u32 scatter cursors (256 KB)
#define WS_STARTS 524288                 // 65536 u32 segment starts (256 KB)
#define WS_SORT   786432                 // 500000 i32 (2 MB)
#define WS_WPK    2883456                // 18432 f16 frag-packed weights (36864 B)
#define WS_PART   2920320                // 256 u32 block partials (1 KB)
#define WS_FEAT   2921344                // 500000*64 f16 feature rows (64 MB)
#define WS_NEED   (WS_FEAT + (size_t)NPTS * COUT * 2)

#define PT_BLOCKS ((NPTS + 255) / 256)   // 1954 (aux kernels, 256 thr)
#define MB_BLOCKS ((NPTS + 511) / 512)   // 977  (main kernel, 512 thr)

#define W_HALFS   18432                  // (7+2)*4 frags * 64 lanes * 8 halfs
#define W1_FRAGS  28                     // 7 k-steps * 4 ch-tiles
#define H_STRIDE  72                     // halfs per staged row (144 B, 16B-aligned)
#define PS_WAVE   (16 * H_STRIDE)        // per-wave P staging (16 rows)

typedef _Float16 f16x8 __attribute__((ext_vector_type(8)));
typedef float    f32x4 __attribute__((ext_vector_type(4)));

__device__ __forceinline__ int cell_index(float v) {
    float nf = fminf(fmaxf((v + 1.0f) * 0.5f, 0.0f), 1.0f);
    int i = (int)floorf(nf * 256.0f);
    return i > 255 ? 255 : i;
}

__device__ __forceinline__ int flat_of(const float* pos, int p, int a1, int a2) {
    float pa1 = pos[p * 3 + a1];
    float pa2 = pos[p * 3 + a2];
    return cell_index(pa1) * GRID_W + cell_index(pa2);
}

// K0: fused weight-pack (B-fragment order) + cell histogram.
// B-frag (16x16x32): lane holds B[k][n], n = lane&15, k = (lane>>4)*8 + j.
__global__ void pack_hist_kernel(const float* __restrict__ W1,
                                 const float* __restrict__ W2,
                                 const float* __restrict__ pos,
                                 const int* __restrict__ ax1p,
                                 const int* __restrict__ ax2p,
                                 _Float16* __restrict__ wpk,
                                 unsigned int* __restrict__ hist)
{
    int i = blockIdx.x * 256 + threadIdx.x;
    if (i < W_HALFS) {
        int j = i & 7, lane = (i >> 3) & 63, f = i >> 9;
        int k  = ((f < W1_FRAGS) ? (f >> 2) : ((f - W1_FRAGS) >> 2)) * 32 + ((lane >> 4) << 3) + j;
        int ch = (f & 3) * 16 + (lane & 15);
        float v;
        if (f < W1_FRAGS) v = (k < 208) ? W1[k * 64 + ch] : 0.0f;
        else              v = W2[k * 64 + ch];
        wpk[i] = (_Float16)v;
    }
    if (i < NPTS)
        atomicAdd(&hist[flat_of(pos, i, ax1p[0], ax2p[0])], 1u);
}

// K1a: per-256-cell-chunk sums (coalesced)
__global__ void scan_sum_kernel(const unsigned int* __restrict__ hist,
                                unsigned int* __restrict__ part)
{
    __shared__ unsigned int sc[256];
    const int t = threadIdx.x;
    sc[t] = hist[blockIdx.x * 256 + t];
    __syncthreads();
    for (int off = 128; off > 0; off >>= 1) {
        if (t < off) sc[t] += sc[t + off];
        __syncthreads();
    }
    if (t == 0) part[blockIdx.x] = sc[0];
}

// K1b: exclusive scan of the 256 partials (single tiny block)
__global__ void scan_top_kernel(unsigned int* __restrict__ part)
{
    __shared__ unsigned int sc[256];
    const int t = threadIdx.x;
    unsigned int v = part[t];
    sc[t] = v;
    __syncthreads();
    for (int off = 1; off < 256; off <<= 1) {
        unsigned int add = (t >= off) ? sc[t - off] : 0u;
        __syncthreads();
        sc[t] += add;
        __syncthreads();
    }
    part[t] = sc[t] - v;   // exclusive
}

// K1c: per-chunk exclusive scan + chunk base -> cursors & starts (coalesced)
__global__ void scan_apply_kernel(const unsigned int* __restrict__ hist,
                                  const unsigned int* __restrict__ part,
                                  unsigned int* __restrict__ cur,
                                  unsigned int* __restrict__ starts)
{
    __shared__ unsigned int sc[256];
    const int t = threadIdx.x;
    unsigned int v = hist[blockIdx.x * 256 + t];
    sc[t] = v;
    __syncthreads();
    for (int off = 1; off < 256; off <<= 1) {
        unsigned int add = (t >= off) ? sc[t - off] : 0u;
        __syncthreads();
        sc[t] += add;
        __syncthreads();
    }
    unsigned int e = sc[t] - v + part[blockIdx.x];
    cur[blockIdx.x * 256 + t]    = e;
    starts[blockIdx.x * 256 + t] = e;
}

// K2: scatter point ids into sorted order (cur mutated into running cursors)
__global__ void scatter_kernel(const float* __restrict__ pos,
                               const int* __restrict__ ax1p,
                               const int* __restrict__ ax2p,
                               unsigned int* __restrict__ cur,
                               int* __restrict__ sorted)
{
    int p = blockIdx.x * 256 + threadIdx.x;
    if (p >= NPTS) return;
    int flat = flat_of(pos, p, ax1p[0], ax2p[0]);
    unsigned int dst = atomicAdd(&cur[flat], 1u);
    sorted[dst] = p;
}

// K3: MFMA MLP. Wave = 64 sorted points (4 row-tiles of 16).
// use_feat=1: dense coalesced fp16 feature-row writes to featbuf[slot] (no atomics).
// use_feat=0: fallback — per-tile segmented fp32-atomic reduce (round-7 path).
__global__ __launch_bounds__(512, 4)
void mlp_mfma_kernel(const float* __restrict__ pos,
                     const float* __restrict__ feats,
                     const _Float16* __restrict__ wpk,
                     const float* __restrict__ b1,
                     const float* __restrict__ ln_g,
                     const float* __restrict__ ln_b,
                     const float* __restrict__ b2,
                     const int*   __restrict__ ax1p,
                     const int*   __restrict__ ax2p,
                     const int*   __restrict__ sorted,
                     _Float16* __restrict__ featbuf,
                     float* __restrict__ outSums,
                     int use_feat)
{
    __shared__ __align__(16) _Float16 WF[W_HALFS];        // 36864 B
    __shared__ __align__(16) _Float16 PS[8 * PS_WAVE];    // 18432 B (per-wave 16 rows)

    // stage frag-packed weights (coalesced 16B copies)
    {
        const uint4* src = (const uint4*)wpk;
        uint4* dst = (uint4*)WF;
        for (int i = threadIdx.x; i < W_HALFS / 8; i += 512) dst[i] = src[i];
    }

    const int lane = threadIdx.x & 63;
    const int wv   = threadIdx.x >> 6;
    const int g    = lane >> 4;        // quad
    const int n    = lane & 15;
    _Float16* Pw = PS + wv * PS_WAVE;

    const int slot   = blockIdx.x * 512 + threadIdx.x;
    const bool valid = (slot < NPTS);
    const int a1 = ax1p[0], a2 = ax2p[0];
    int myc;
    {
        int p0 = valid ? sorted[slot] : 0;
        myc = valid ? flat_of(pos, p0, a1, a2) : 0x7FFFFFFF;
    }
    int prevc = __shfl_up(myc, 1);
    unsigned long long heads = __ballot(lane == 0 || myc != prevc);

    // per-channel params for ch = n + 16c
    float b1v[4], b2v[4], lgv[4], lbv[4];
    #pragma unroll
    for (int c = 0; c < 4; ++c) {
        int ch = n + 16 * c;
        b1v[c] = b1[ch]; b2v[c] = b2[ch]; lgv[c] = ln_g[ch]; lbv[c] = ln_b[ch];
    }

    // per-tile point data: lane serves point (t*16 + n)
    int   pt[4];
    float ppx[4], ppy[4], ppz[4];
    const int wbase = blockIdx.x * 512 + wv * 64;
    #pragma unroll
    for (int t = 0; t < 4; ++t) {
        int st = wbase + t * 16 + n;
        int p  = (st < NPTS) ? sorted[st] : 0;
        pt[t]  = p;
        ppx[t] = pos[3 * p + 0];
        ppy[t] = pos[3 * p + 1];
        ppz[t] = pos[3 * p + 2];
    }

    // prefetch feats (used by g<2 lanes in s=0) — all 8 loads in flight
    float4 fA[4], fB[4];
    if (g < 2) {
        #pragma unroll
        for (int t = 0; t < 4; ++t) {
            const float4* fr = (const float4*)(feats + (size_t)pt[t] * CIN + g * 8);
            fA[t] = fr[0]; fB[t] = fr[1];
        }
    }

    __syncthreads();   // WF visible

    // ---- GEMM1: acc[t][c] (16 pts x 16 ch), K = 224 (208 + zero pad) ------
    f32x4 acc[4][4];
    #pragma unroll
    for (int t = 0; t < 4; ++t)
        #pragma unroll
        for (int c = 0; c < 4; ++c)
            acc[t][c] = (f32x4){0.0f, 0.0f, 0.0f, 0.0f};

    #pragma unroll
    for (int s = 0; s < 7; ++s) {
        f16x8 af[4];
        #pragma unroll
        for (int t = 0; t < 4; ++t) {
            int k0 = s * 32 + g * 8;
            f16x8 a;
            if (s == 0 && g < 2) {               // feats rows (prefetched)
                a[0] = (_Float16)fA[t].x; a[1] = (_Float16)fA[t].y;
                a[2] = (_Float16)fA[t].z; a[3] = (_Float16)fA[t].w;
                a[4] = (_Float16)fB[t].x; a[5] = (_Float16)fB[t].y;
                a[6] = (_Float16)fB[t].z; a[7] = (_Float16)fB[t].w;
            } else if (k0 >= 208) {              // zero pad (s==6, g>=2)
                #pragma unroll
                for (int j = 0; j < 8; ++j) a[j] = (_Float16)0.0f;
            } else {                             // PE: e = k0-16 = d*64+sc*32+f0
                int e  = k0 - 16;
                int d  = e >> 6;
                int sc = (e >> 5) & 1;
                int f0 = e & 31;
                float pv  = (d == 0) ? ppx[t] : ((d == 1) ? ppy[t] : ppz[t]);
                float ang = pv * 1.57079632679489662f * exp2f((float)f0 * 0.03125f);
                #pragma unroll
                for (int j = 0; j < 8; ++j) {
                    float v = sc ? __cosf(ang) : __sinf(ang);
                    a[j] = (_Float16)v;
                    ang *= 1.02189714865411668f;   // 2^(1/32)
                }
            }
            af[t] = a;
        }
        #pragma unroll
        for (int c = 0; c < 4; ++c) {
            f16x8 bf = ((const f16x8*)WF)[(s * 4 + c) * 64 + lane];
            #pragma unroll
            for (int t = 0; t < 4; ++t)
                acc[t][c] = __builtin_amdgcn_mfma_f32_16x16x32_f16(af[t], bf, acc[t][c], 0, 0, 0);
        }
    }

    // ---- per tile: LN + GELU -> PS, GEMM2, epilogue -----------------------
    // D layout: lane holds D[row = 4g + r][ch = n + 16c], r = 0..3
    #pragma unroll
    for (int t = 0; t < 4; ++t) {
        f32x4 s1 = (f32x4){0.0f, 0.0f, 0.0f, 0.0f};
        f32x4 s2 = (f32x4){0.0f, 0.0f, 0.0f, 0.0f};
        #pragma unroll
        for (int c = 0; c < 4; ++c) {
            #pragma unroll
            for (int r = 0; r < 4; ++r) {
                float x = acc[t][c][r] + b1v[c];
                acc[t][c][r] = x;
                s1[r] += x;
                s2[r] += x * x;
            }
        }
        #pragma unroll
        for (int m = 1; m <= 8; m <<= 1) {
            #pragma unroll
            for (int r = 0; r < 4; ++r) {
                s1[r] += __shfl_xor(s1[r], m);
                s2[r] += __shfl_xor(s2[r], m);
            }
        }
        #pragma unroll
        for (int r = 0; r < 4; ++r) {
            float mu   = s1[r] * (1.0f / 64.0f);
            float var  = s2[r] * (1.0f / 64.0f) - mu * mu;
            float rstd = __builtin_amdgcn_rsqf(var + 1e-5f);
            int lrow = 4 * g + r;
            #pragma unroll
            for (int c = 0; c < 4; ++c) {
                float x  = (acc[t][c][r] - mu) * rstd * lgv[c] + lbv[c];
                float u  = x * (0.7978845608028654f + 0.0356774081363001f * x * x);
                float e  = __expf(2.0f * u);
                float th = 1.0f - 2.0f * __builtin_amdgcn_rcpf(e + 1.0f);
                float gv = 0.5f * x * (1.0f + th);
                Pw[lrow * H_STRIDE + n + 16 * c] = (_Float16)gv;
            }
        }

        // GEMM2 for this tile
        f32x4 acc2[4];
        #pragma unroll
        for (int c = 0; c < 4; ++c) acc2[c] = (f32x4){0.0f, 0.0f, 0.0f, 0.0f};
        #pragma unroll
        for (int s = 0; s < 2; ++s) {
            f16x8 a2f = *(const f16x8*)(Pw + n * H_STRIDE + s * 32 + g * 8);
            #pragma unroll
            for (int c = 0; c < 4; ++c) {
                f16x8 bf = ((const f16x8*)WF)[(W1_FRAGS + s * 4 + c) * 64 + lane];
                acc2[c] = __builtin_amdgcn_mfma_f32_16x16x32_f16(a2f, bf, acc2[c], 0, 0, 0);
            }
        }
        #pragma unroll
        for (int c = 0; c < 4; ++c)
            #pragma unroll
            for (int r = 0; r < 4; ++r)
                acc2[c][r] += b2v[c];

        if (use_feat) {
            // stage D2 -> Pw, then dense coalesced fp16 row writes (no atomics)
            #pragma unroll
            for (int r = 0; r < 4; ++r) {
                int lrow = 4 * g + r;
                #pragma unroll
                for (int c = 0; c < 4; ++c)
                    Pw[lrow * H_STRIDE + n + 16 * c] = (_Float16)acc2[c][r];
            }
            // wave writes 16 rows x 128 B contiguous: 4 lanes/row, 32 B each
            int lrow  = lane >> 2;
            int gslot = wbase + t * 16 + lrow;
            if (gslot < NPTS) {
                const uint4* src = (const uint4*)(Pw + lrow * H_STRIDE + (lane & 3) * 16);
                uint4* dst = (uint4*)(featbuf + (size_t)gslot * COUT + (lane & 3) * 16);
                dst[0] = src[0];
                dst[1] = src[1];
            }
        } else {
            // fallback: segmented fp32-atomic reduce over this tile's 16 rows
            unsigned int ht = (unsigned int)((heads >> (t * 16)) & 0xFFFFull) | 1u;
            int s = 0;
            while (s < 16) {
                unsigned int rem = ht & ~((2u << s) - 1u);
                int e = rem ? (__ffs(rem) - 1) : 16;
                int cellr = __shfl(myc, t * 16 + s);
                f32x4 part;
                #pragma unroll
                for (int c = 0; c < 4; ++c) {
                    float pc = 0.0f;
                    #pragma unroll
                    for (int r = 0; r < 4; ++r) {
                        int row = 4 * g + r;
                        pc += (row >= s && row < e) ? acc2[c][r] : 0.0f;
                    }
                    pc += __shfl_xor(pc, 16);
                    pc += __shfl_xor(pc, 32);
                    part[c] = pc;
                }
                if (g == 0 && cellr != 0x7FFFFFFF) {
                    #pragma unroll
                    for (int c = 0; c < 4; ++c)
                        unsafeAtomicAdd(&outSums[(n + 16 * c) * NCELL + cellr], part[c]);
                }
                s = e;
            }
        }
    }
}

// K4: per-cell dense reduce from featbuf + divide + coalesced store.
// Block = 256 thr = 4 waves; block covers 64 cells; wave = 16 cells serially.
__global__ __launch_bounds__(256)
void reduce_kernel(const _Float16* __restrict__ featbuf,
                   const unsigned int* __restrict__ starts,
                   const unsigned int* __restrict__ hist,
                   float* __restrict__ out)
{
    __shared__ float R[64][65];
    const int lane = threadIdx.x & 63;
    const int wv   = threadIdx.x >> 6;
    const int cbase = blockIdx.x * 64;

    for (int i = 0; i < 16; ++i) {
        int cl   = wv * 16 + i;
        int cell = cbase + cl;
        unsigned int s0  = starts[cell];
        unsigned int cnt = hist[cell];
        float acc0 = 0.0f, acc1 = 0.0f;
        unsigned int k = 0;
        for (; k + 2 <= cnt; k += 2) {   // 2 independent chains
            acc0 += (float)featbuf[(size_t)(s0 + k)     * COUT + lane];
            acc1 += (float)featbuf[(size_t)(s0 + k + 1) * COUT + lane];
        }
        if (k < cnt)
            acc0 += (float)featbuf[(size_t)(s0 + k) * COUT + lane];
        R[cl][lane] = (acc0 + acc1) / fmaxf((float)cnt, 1.0f);
    }
    __syncthreads();

    // store coalesced: consecutive cells for a fixed channel
    for (int ch = wv; ch < COUT; ch += 4)
        out[ch * NCELL + cbase + lane] = R[lane][ch];
}

// K5 (fallback only): divide by counts, in place on d_out
__global__ void finalize_kernel(float* __restrict__ out,
                                const unsigned int* __restrict__ hist)
{
    int t = blockIdx.x * 256 + threadIdx.x;
    float c = (float)hist[t & (NCELL - 1)];
    out[t] = out[t] / fmaxf(c, 1.0f);
}

extern "C" void kernel_launch(void* const* d_in, const int* in_sizes, int n_in,
                              void* d_out, int out_size, void* d_ws, size_t ws_size,
                              hipStream_t stream) {
    (void)in_sizes; (void)n_in; (void)out_size;
    const float* pos   = (const float*)d_in[0];
    const float* feats = (const float*)d_in[1];
    const float* W1    = (const float*)d_in[2];
    const float* b1    = (const float*)d_in[3];
    const float* ln_g  = (const float*)d_in[4];
    const float* ln_b  = (const float*)d_in[5];
    const float* W2    = (const float*)d_in[6];
    const float* b2    = (const float*)d_in[7];
    const int*   ax1   = (const int*)d_in[8];
    const int*   ax2   = (const int*)d_in[9];

    char* ws = (char*)d_ws;
    unsigned int* hist   = (unsigned int*)(ws + WS_HIST);
    unsigned int* cur    = (unsigned int*)(ws + WS_CUR);
    unsigned int* starts = (unsigned int*)(ws + WS_STARTS);
    int*          sorted = (int*)(ws + WS_SORT);
    _Float16*     wpk    = (_Float16*)(ws + WS_WPK);
    unsigned int* part   = (unsigned int*)(ws + WS_PART);
    _Float16*     featbf = (_Float16*)(ws + WS_FEAT);

    float* out = (float*)d_out;
    const int use_feat = (ws_size >= WS_NEED) ? 1 : 0;

    hipMemsetAsync(hist, 0, NCELL * sizeof(unsigned int), stream);
    if (!use_feat)
        hipMemsetAsync(d_out, 0, (size_t)COUT * NCELL * sizeof(float), stream);

    pack_hist_kernel<<<PT_BLOCKS, 256, 0, stream>>>(W1, W2, pos, ax1, ax2, wpk, hist);
    scan_sum_kernel<<<256, 256, 0, stream>>>(hist, part);
    scan_top_kernel<<<1, 256, 0, stream>>>(part);
    scan_apply_kernel<<<256, 256, 0, stream>>>(hist, part, cur, starts);
    scatter_kernel<<<PT_BLOCKS, 256, 0, stream>>>(pos, ax1, ax2, cur, sorted);
    mlp_mfma_kernel<<<MB_BLOCKS, 512, 0, stream>>>(
        pos, feats, wpk, b1, ln_g, ln_b, b2, ax1, ax2, sorted, featbf, out, use_feat);
    if (use_feat)
        reduce_kernel<<<NCELL / 64, 256, 0, stream>>>(featbf, starts, hist, out);
    else
        finalize_kernel<<<(COUT * NCELL) / 256, 256, 0, stream>>>(out, hist);
}